// Round 21
// baseline (143.846 us; speedup 1.0000x reference)
//
#include <hip/hip_runtime.h>
#include <math.h>

constexpr int Bb = 4, Cc = 64, Hh = 256, Ww = 256;
constexpr int RR = 4;             // output rows per block (amp 1.5x)
constexpr int NSTRIP = Hh / RR;   // 64
constexpr int NBLK = Bb * NSTRIP; // 256 entropy blocks = 1 per CU
constexpr int NPX = Bb * Hh * Ww; // 262144 output pixels
constexpr int NPX4 = NPX / 4;

#define LOG2E 1.44269504088896340736f

__device__ __forceinline__ unsigned int fenc(float f) {
  unsigned int u = __float_as_uint(f);
  return (u & 0x80000000u) ? ~u : (u | 0x80000000u);
}
__device__ __forceinline__ float fdec(unsigned int k) {
  return __uint_as_float((k & 0x80000000u) ? (k ^ 0x80000000u) : ~k);
}

// Rescaled entropy (affine-invariant under final min/max normalize):
//   e' = log2(s) - (sum u*a)/s,  u = v*log2e, a = 2^u, s = 3x3 box of a.
//
// Structure (r19, best 24.5us): block (64,16) = 16 waves, lane = 4 cols
// (float4 full row), ty = 4 channels, RR = 4 rows, grid = 256 = 1 block/CU,
// block-local min/max -> pm (non-atomic), then one norm dispatch.
//
// NEW (r21): the 4 channels per ty are processed as TWO INTERLEAVED PAIRS —
// each j-iteration runs two independent exp/shfl/hsum/entropy chains, so
// per-wave ILP hides trans+LDS latency that 4 waves/SIMD TLP cannot
// (r20 showed the kernel is latency-bound, not instruction-bound).
// ~105 VGPR expected — under the 128/wave budget of a single-resident
// 1024-thread block. NOTE: plain __launch_bounds__ (min-waves hints spill,
// r6/r7); all acc indices compile-time (r15).
template <bool CHK>
__device__ __forceinline__ void do_pair(const float* __restrict__ p0,
                                        const float* __restrict__ p1,
                                        int r0, int tx, float (&acc)[RR][4]) {
  float ha0[3][4], hb0[3][4], ha1[3][4], hb1[3][4];
#pragma unroll
  for (int j = 0; j < RR + 2; ++j) {
    const int row = r0 - 1 + j;
    float4 v0 = make_float4(0.f, 0.f, 0.f, 0.f);
    float4 v1 = make_float4(0.f, 0.f, 0.f, 0.f);
    if (!CHK || (row >= 0 && row < Hh)) {
      v0 = *reinterpret_cast<const float4*>(p0 + (size_t)row * Ww);
      v1 = *reinterpret_cast<const float4*>(p1 + (size_t)row * Ww);
    }
    const float* vp0 = &v0.x;
    const float* vp1 = &v1.x;
    float a0[4], b0[4], a1[4], b1[4];
#pragma unroll
    for (int i = 0; i < 4; ++i) {
      float u0 = vp0[i] * LOG2E;
      float u1 = vp1[i] * LOG2E;
      a0[i] = __builtin_amdgcn_exp2f(u0);
      a1[i] = __builtin_amdgcn_exp2f(u1);
      b0[i] = u0 * a0[i];
      b1[i] = u1 * a1[i];
    }
    float la0 = __shfl_up(a0[3], 1, 64),  la1 = __shfl_up(a1[3], 1, 64);
    float lb0 = __shfl_up(b0[3], 1, 64),  lb1 = __shfl_up(b1[3], 1, 64);
    float ra0 = __shfl_down(a0[0], 1, 64), ra1 = __shfl_down(a1[0], 1, 64);
    float rb0 = __shfl_down(b0[0], 1, 64), rb1 = __shfl_down(b1[0], 1, 64);
    la0 = (tx == 0) ? 1.f : la0;   lb0 = (tx == 0) ? 0.f : lb0;
    la1 = (tx == 0) ? 1.f : la1;   lb1 = (tx == 0) ? 0.f : lb1;
    ra0 = (tx == 63) ? 1.f : ra0;  rb0 = (tx == 63) ? 0.f : rb0;
    ra1 = (tx == 63) ? 1.f : ra1;  rb1 = (tx == 63) ? 0.f : rb1;
    const int s0 = j % 3;  // compile-time (loop unrolled)
    {
      float t01 = a0[0] + a0[1], t23 = a0[2] + a0[3];
      ha0[s0][0] = la0 + t01;  ha0[s0][1] = t01 + a0[2];
      ha0[s0][2] = a0[1] + t23; ha0[s0][3] = t23 + ra0;
    }
    {
      float t01 = b0[0] + b0[1], t23 = b0[2] + b0[3];
      hb0[s0][0] = lb0 + t01;  hb0[s0][1] = t01 + b0[2];
      hb0[s0][2] = b0[1] + t23; hb0[s0][3] = t23 + rb0;
    }
    {
      float t01 = a1[0] + a1[1], t23 = a1[2] + a1[3];
      ha1[s0][0] = la1 + t01;  ha1[s0][1] = t01 + a1[2];
      ha1[s0][2] = a1[1] + t23; ha1[s0][3] = t23 + ra1;
    }
    {
      float t01 = b1[0] + b1[1], t23 = b1[2] + b1[3];
      hb1[s0][0] = lb1 + t01;  hb1[s0][1] = t01 + b1[2];
      hb1[s0][2] = b1[1] + t23; hb1[s0][3] = t23 + rb1;
    }
    if (j >= 2) {
      const int orow = j - 2;   // compile-time
#pragma unroll
      for (int i = 0; i < 4; ++i) {
        float s_0 = ha0[0][i] + ha0[1][i] + ha0[2][i];
        float w_0 = hb0[0][i] + hb0[1][i] + hb0[2][i];
        float s_1 = ha1[0][i] + ha1[1][i] + ha1[2][i];
        float w_1 = hb1[0][i] + hb1[1][i] + hb1[2][i];
        float e0 = __builtin_amdgcn_logf(s_0) - w_0 * __builtin_amdgcn_rcpf(s_0);
        float e1 = __builtin_amdgcn_logf(s_1) - w_1 * __builtin_amdgcn_rcpf(s_1);
        acc[orow][i] += e0 + e1;
      }
    }
  }
}

template <int FB>
__global__ __launch_bounds__(1024) void entropy_kernel(const float* __restrict__ x,
                                                       float* __restrict__ e,
                                                       float* __restrict__ pm,
                                                       unsigned int* __restrict__ stats) {
  const int bx = blockIdx.x;
  const int strip = bx & (NSTRIP - 1);
  const int b = bx >> 6;
  const int r0 = strip * RR;
  const int tx = threadIdx.x;   // 0..63
  const int ty = threadIdx.y;   // 0..15
  const int w0 = tx * 4;

  const size_t planeStride = (size_t)Hh * Ww;
  const float* xb = x + ((size_t)b * Cc + ty * 4) * planeStride + w0;
  const bool interior = (strip != 0) && (strip != NSTRIP - 1);

  float acc[RR][4];
#pragma unroll
  for (int o = 0; o < RR; ++o)
#pragma unroll
    for (int i = 0; i < 4; ++i) acc[o][i] = 0.f;

  if (interior) {
    do_pair<false>(xb,                  xb + planeStride,     r0, tx, acc);
    do_pair<false>(xb + 2 * planeStride, xb + 3 * planeStride, r0, tx, acc);
  } else {
    do_pair<true>(xb,                  xb + planeStride,     r0, tx, acc);
    do_pair<true>(xb + 2 * planeStride, xb + 3 * planeStride, r0, tx, acc);
  }

  // Two-stage reduce of the 16 ty channel groups.
  __shared__ float red[16][RR][4][64];   // 64 KiB
  __shared__ float red2[4][RR][4][64];   // 16 KiB (fits: 1 block/CU)
#pragma unroll
  for (int o = 0; o < RR; ++o)
#pragma unroll
    for (int i = 0; i < 4; ++i) red[ty][o][i][tx] = acc[o][i];
  __syncthreads();
  {
    const int o = ty & 3, q = ty >> 2;   // all 16 waves work
#pragma unroll
    for (int i = 0; i < 4; ++i)
      red2[q][o][i][tx] = red[q * 4 + 0][o][i][tx] + red[q * 4 + 1][o][i][tx] +
                          red[q * 4 + 2][o][i][tx] + red[q * 4 + 3][o][i][tx];
  }
  __syncthreads();

  float mn = INFINITY, mx = -INFINITY;
  if (ty < RR) {
    const size_t px = (size_t)(b * Hh + r0 + ty) * Ww + w0;
    float vsum[4];
#pragma unroll
    for (int i = 0; i < 4; ++i)
      vsum[i] = red2[0][ty][i][tx] + red2[1][ty][i][tx] +
                red2[2][ty][i][tx] + red2[3][ty][i][tx];
    *reinterpret_cast<float4*>(e + px) =
        make_float4(vsum[0], vsum[1], vsum[2], vsum[3]);
    mn = fminf(fminf(vsum[0], vsum[1]), fminf(vsum[2], vsum[3]));
    mx = fmaxf(fmaxf(vsum[0], vsum[1]), fmaxf(vsum[2], vsum[3]));
#pragma unroll
    for (int off = 32; off > 0; off >>= 1) {
      mn = fminf(mn, __shfl_down(mn, off, 64));
      mx = fmaxf(mx, __shfl_down(mx, off, 64));
    }
  }
  __shared__ float smn[RR], smx[RR];
  if (ty < RR && tx == 0) { smn[ty] = mn; smx[ty] = mx; }
  __syncthreads();
  if (ty == 0 && tx == 0) {
    mn = fminf(fminf(smn[0], smn[1]), fminf(smn[2], smn[3]));
    mx = fmaxf(fmaxf(smx[0], smx[1]), fmaxf(smx[2], smx[3]));
    if (FB == 0) {
      pm[bx] = mn;           // every slot written -> no init
      pm[NBLK + bx] = mx;
    } else {
      atomicMin(&stats[b], fenc(mn));
      atomicMax(&stats[4 + b], fenc(mx));
    }
  }
}

// Reduce this batch's 64 pm pairs in one wave, then normalize.
__global__ __launch_bounds__(256) void norm_ws(float* __restrict__ e,
                                               const float* __restrict__ pm) {
  const int bx = blockIdx.x;
  const int b = bx >> 6;
  const int lane = threadIdx.x & 63;
  float mn = pm[b * 64 + lane];
  float mx = pm[NBLK + b * 64 + lane];
#pragma unroll
  for (int off = 32; off > 0; off >>= 1) {
    mn = fminf(mn, __shfl_down(mn, off, 64));
    mx = fmaxf(mx, __shfl_down(mx, off, 64));
  }
  mn = __shfl(mn, 0, 64);
  mx = __shfl(mx, 0, 64);
  const float inv = 1.0f / fmaxf(mx - mn, 1e-6f);

  const int t = bx * 256 + threadIdx.x;
  float4 v = reinterpret_cast<float4*>(e)[t];
  v.x = (v.x - mn) * inv;
  v.y = (v.y - mn) * inv;
  v.z = (v.z - mn) * inv;
  v.w = (v.w - mn) * inv;
  reinterpret_cast<float4*>(e)[t] = v;
}

// Fallback normalize from atomic stats.
__global__ __launch_bounds__(256) void norm_atomic(float* __restrict__ e,
                                                   const unsigned int* __restrict__ stats) {
  const int t = blockIdx.x * 256 + threadIdx.x;
  const int b = t >> 14;
  const float mn = fdec(stats[b]);
  const float mx = fdec(stats[4 + b]);
  const float inv = 1.0f / fmaxf(mx - mn, 1e-6f);
  float4 v = reinterpret_cast<float4*>(e)[t];
  v.x = (v.x - mn) * inv;
  v.y = (v.y - mn) * inv;
  v.z = (v.z - mn) * inv;
  v.w = (v.w - mn) * inv;
  reinterpret_cast<float4*>(e)[t] = v;
}

extern "C" void kernel_launch(void* const* d_in, const int* in_sizes, int n_in,
                              void* d_out, int out_size, void* d_ws, size_t ws_size,
                              hipStream_t stream) {
  const float* x = (const float*)d_in[0];
  float* out = (float*)d_out;

  const size_t ws_needed = (size_t)(2 * NBLK) * sizeof(float);  // 2 KB
  if (ws_size >= ws_needed) {
    float* pm = (float*)d_ws;  // [NBLK min][NBLK max]
    entropy_kernel<0><<<dim3(NBLK), dim3(64, 16), 0, stream>>>(x, out, pm, nullptr);
    norm_ws<<<dim3(NPX4 / 256), dim3(256), 0, stream>>>(out, pm);
  } else {
    unsigned int* stats = (unsigned int*)d_ws;  // 8 uints
    hipMemsetAsync(stats, 0xFF, 4 * sizeof(unsigned int), stream);
    hipMemsetAsync(stats + 4, 0x00, 4 * sizeof(unsigned int), stream);
    entropy_kernel<1><<<dim3(NBLK), dim3(64, 16), 0, stream>>>(x, out, nullptr, stats);
    norm_atomic<<<dim3(NPX4 / 256), dim3(256), 0, stream>>>(out, stats);
  }
}

// Round 22
// 31.198 us; speedup vs baseline: 4.6108x; 4.6108x over previous
//
#include <hip/hip_runtime.h>
#include <math.h>

constexpr int Bb = 4, Cc = 64, Hh = 256, Ww = 256;
constexpr int RR = 2;             // output rows per block (amp 2.0x)
constexpr int NSTRIP = Hh / RR;   // 128
constexpr int NBLK = Bb * NSTRIP; // 512 entropy blocks = 2 per CU
constexpr int NPX = Bb * Hh * Ww; // 262144 output pixels
constexpr int NPX4 = NPX / 4;

#define LOG2E 1.44269504088896340736f

__device__ __forceinline__ unsigned int fenc(float f) {
  unsigned int u = __float_as_uint(f);
  return (u & 0x80000000u) ? ~u : (u | 0x80000000u);
}
__device__ __forceinline__ float fdec(unsigned int k) {
  return __uint_as_float((k & 0x80000000u) ? (k ^ 0x80000000u) : ~k);
}

// Rescaled entropy (affine-invariant under final min/max normalize):
//   e' = log2(s) - (sum u*a)/s,  u = v*log2e, a = 2^u, s = 3x3 box of a.
//
// Slim RR=2 geometry targeting the 64-VGPR / 2-blocks-per-CU class:
// block (64,16) = 16 waves; lane = 4 cols (float4 full row; halos are image
// edges = constants); ty = 4 channels (rolled cc loop). RR=2 rows/block,
// grid = 4 x 128 = 512 blocks -> 2 blocks/CU -> 8 waves/SIMD IF VGPR<=64.
// Per-thread state is minimized for that: NO hsum ring — each row's
// horizontal sums accumulate directly into the s/w accumulators of the
// 1-2 output rows it overlaps (row j feeds o=0 for j<=2, o=1 for j>=1;
// all compile-time). Live state ~50 regs.
// r17 failed this shape at 31.5us because its body exceeded 64 VGPR ->
// 1 block/CU -> pure +33% amplification cost. r21 showed the compiler
// CAPS 1024-thread blocks at 64 VGPR, so a <=64-reg body is the fit.
// FB=0: block min/max -> pm[bx] non-atomic. FB=1: atomic fallback.
// NOTE: plain __launch_bounds__ only (min-waves hints spill, r6/r7);
// all acc indices compile-time (r15).
template <int FB>
__global__ __launch_bounds__(1024) void entropy_kernel(const float* __restrict__ x,
                                                       float* __restrict__ e,
                                                       float* __restrict__ pm,
                                                       unsigned int* __restrict__ stats) {
  const int bx = blockIdx.x;
  const int strip = bx & (NSTRIP - 1);
  const int b = bx >> 7;
  const int r0 = strip * RR;
  const int tx = threadIdx.x;   // 0..63
  const int ty = threadIdx.y;   // 0..15
  const int w0 = tx * 4;

  const size_t planeStride = (size_t)Hh * Ww;
  const float* xb = x + ((size_t)b * Cc + ty * 4) * planeStride + w0;
  const bool interior = (strip != 0) && (strip != NSTRIP - 1);

  float acc[RR][4];
#pragma unroll
  for (int o = 0; o < RR; ++o)
#pragma unroll
    for (int i = 0; i < 4; ++i) acc[o][i] = 0.f;

#define CHANNEL_BODY(CHK)                                                     \
  {                                                                           \
    float s0[4] = {0.f, 0.f, 0.f, 0.f}, w0a[4] = {0.f, 0.f, 0.f, 0.f};       \
    float s1[4] = {0.f, 0.f, 0.f, 0.f}, w1a[4] = {0.f, 0.f, 0.f, 0.f};       \
    _Pragma("unroll")                                                         \
    for (int j = 0; j < RR + 2; ++j) {    /* 4 rows */                        \
      const int row = r0 - 1 + j;                                             \
      float4 v = make_float4(0.f, 0.f, 0.f, 0.f);                             \
      if (!CHK || (row >= 0 && row < Hh))                                     \
        v = *reinterpret_cast<const float4*>(plane + (size_t)row * Ww);       \
      const float* vp = &v.x;                                                 \
      float a[4], bb[4];                                                      \
      _Pragma("unroll")                                                       \
      for (int i = 0; i < 4; ++i) {                                           \
        float u = vp[i] * LOG2E;                                              \
        a[i] = __builtin_amdgcn_exp2f(u);                                     \
        bb[i] = u * a[i];                                                     \
      }                                                                       \
      float la = __shfl_up(a[3], 1, 64);                                      \
      float lb = __shfl_up(bb[3], 1, 64);                                     \
      float ra = __shfl_down(a[0], 1, 64);                                    \
      float rb = __shfl_down(bb[0], 1, 64);                                   \
      la = (tx == 0) ? 1.f : la;   lb = (tx == 0) ? 0.f : lb;                 \
      ra = (tx == 63) ? 1.f : ra;  rb = (tx == 63) ? 0.f : rb;                \
      float ha[4], hb[4];                                                     \
      {                                                                       \
        float t01 = a[0] + a[1], t23 = a[2] + a[3];                           \
        ha[0] = la + t01;  ha[1] = t01 + a[2];                                \
        ha[2] = a[1] + t23; ha[3] = t23 + ra;                                 \
      }                                                                       \
      {                                                                       \
        float t01 = bb[0] + bb[1], t23 = bb[2] + bb[3];                       \
        hb[0] = lb + t01;  hb[1] = t01 + bb[2];                               \
        hb[2] = bb[1] + t23; hb[3] = t23 + rb;                                \
      }                                                                       \
      if (j <= 2) {   /* compile-time: rows 0..2 feed output 0 */             \
        _Pragma("unroll")                                                     \
        for (int i = 0; i < 4; ++i) { s0[i] += ha[i]; w0a[i] += hb[i]; }      \
      }                                                                       \
      if (j >= 1) {   /* compile-time: rows 1..3 feed output 1 */             \
        _Pragma("unroll")                                                     \
        for (int i = 0; i < 4; ++i) { s1[i] += ha[i]; w1a[i] += hb[i]; }      \
      }                                                                       \
    }                                                                         \
    _Pragma("unroll")                                                         \
    for (int i = 0; i < 4; ++i) {                                             \
      acc[0][i] += __builtin_amdgcn_logf(s0[i]) -                             \
                   w0a[i] * __builtin_amdgcn_rcpf(s0[i]);                     \
      acc[1][i] += __builtin_amdgcn_logf(s1[i]) -                             \
                   w1a[i] * __builtin_amdgcn_rcpf(s1[i]);                     \
    }                                                                         \
  }

  if (interior) {
#pragma unroll 1
    for (int cc = 0; cc < 4; ++cc) {
      const float* plane = xb + (size_t)cc * planeStride;
      CHANNEL_BODY(false)
    }
  } else {
#pragma unroll 1
    for (int cc = 0; cc < 4; ++cc) {
      const float* plane = xb + (size_t)cc * planeStride;
      CHANNEL_BODY(true)
    }
  }
#undef CHANNEL_BODY

  // Reduce the 16 ty channel groups (32 KiB LDS; 2 blocks/CU -> 64 KiB/CU).
  __shared__ float red[16][RR][4][64];
#pragma unroll
  for (int o = 0; o < RR; ++o)
#pragma unroll
    for (int i = 0; i < 4; ++i) red[ty][o][i][tx] = acc[o][i];
  __syncthreads();

  float mn = INFINITY, mx = -INFINITY;
  if (ty < RR) {
    const size_t px = (size_t)(b * Hh + r0 + ty) * Ww + w0;
    float vsum[4];
#pragma unroll
    for (int i = 0; i < 4; ++i) {
      float t = 0.f;
#pragma unroll
      for (int g = 0; g < 16; ++g) t += red[g][ty][i][tx];
      vsum[i] = t;
    }
    *reinterpret_cast<float4*>(e + px) =
        make_float4(vsum[0], vsum[1], vsum[2], vsum[3]);
    mn = fminf(fminf(vsum[0], vsum[1]), fminf(vsum[2], vsum[3]));
    mx = fmaxf(fmaxf(vsum[0], vsum[1]), fmaxf(vsum[2], vsum[3]));
#pragma unroll
    for (int off = 32; off > 0; off >>= 1) {
      mn = fminf(mn, __shfl_down(mn, off, 64));
      mx = fmaxf(mx, __shfl_down(mx, off, 64));
    }
  }
  __shared__ float smn[RR], smx[RR];
  if (ty < RR && tx == 0) { smn[ty] = mn; smx[ty] = mx; }
  __syncthreads();
  if (ty == 0 && tx == 0) {
    mn = fminf(smn[0], smn[1]);
    mx = fmaxf(smx[0], smx[1]);
    if (FB == 0) {
      pm[bx] = mn;           // every slot written -> no init
      pm[NBLK + bx] = mx;
    } else {
      atomicMin(&stats[b], fenc(mn));
      atomicMax(&stats[4 + b], fenc(mx));
    }
  }
}

// Reduce this batch's 128 pm pairs (two waves' worth via LDS), normalize.
// Grid 256 blocks x 256 threads, one float4 per thread. Batch b = bx>>6.
__global__ __launch_bounds__(256) void norm_ws(float* __restrict__ e,
                                               const float* __restrict__ pm) {
  const int bx = blockIdx.x;
  const int b = bx >> 6;
  const int k = threadIdx.x & 127;
  float mn = pm[b * 128 + k];
  float mx = pm[NBLK + b * 128 + k];
#pragma unroll
  for (int off = 32; off > 0; off >>= 1) {
    mn = fminf(mn, __shfl_down(mn, off, 64));
    mx = fmaxf(mx, __shfl_down(mx, off, 64));
  }
  __shared__ float smn[4], smx[4];
  const int wave = threadIdx.x >> 6;
  if ((threadIdx.x & 63) == 0) { smn[wave] = mn; smx[wave] = mx; }
  __syncthreads();
  mn = fminf(fminf(smn[0], smn[1]), fminf(smn[2], smn[3]));
  mx = fmaxf(fmaxf(smx[0], smx[1]), fmaxf(smx[2], smx[3]));
  const float inv = 1.0f / fmaxf(mx - mn, 1e-6f);

  const int t = bx * 256 + threadIdx.x;
  float4 v = reinterpret_cast<float4*>(e)[t];
  v.x = (v.x - mn) * inv;
  v.y = (v.y - mn) * inv;
  v.z = (v.z - mn) * inv;
  v.w = (v.w - mn) * inv;
  reinterpret_cast<float4*>(e)[t] = v;
}

// Fallback normalize from atomic stats.
__global__ __launch_bounds__(256) void norm_atomic(float* __restrict__ e,
                                                   const unsigned int* __restrict__ stats) {
  const int t = blockIdx.x * 256 + threadIdx.x;
  const int b = t >> 14;
  const float mn = fdec(stats[b]);
  const float mx = fdec(stats[4 + b]);
  const float inv = 1.0f / fmaxf(mx - mn, 1e-6f);
  float4 v = reinterpret_cast<float4*>(e)[t];
  v.x = (v.x - mn) * inv;
  v.y = (v.y - mn) * inv;
  v.z = (v.z - mn) * inv;
  v.w = (v.w - mn) * inv;
  reinterpret_cast<float4*>(e)[t] = v;
}

extern "C" void kernel_launch(void* const* d_in, const int* in_sizes, int n_in,
                              void* d_out, int out_size, void* d_ws, size_t ws_size,
                              hipStream_t stream) {
  const float* x = (const float*)d_in[0];
  float* out = (float*)d_out;

  const size_t ws_needed = (size_t)(2 * NBLK) * sizeof(float);  // 4 KB
  if (ws_size >= ws_needed) {
    float* pm = (float*)d_ws;  // [NBLK min][NBLK max]
    entropy_kernel<0><<<dim3(NBLK), dim3(64, 16), 0, stream>>>(x, out, pm, nullptr);
    norm_ws<<<dim3(NPX4 / 256), dim3(256), 0, stream>>>(out, pm);
  } else {
    unsigned int* stats = (unsigned int*)d_ws;  // 8 uints
    hipMemsetAsync(stats, 0xFF, 4 * sizeof(unsigned int), stream);
    hipMemsetAsync(stats + 4, 0x00, 4 * sizeof(unsigned int), stream);
    entropy_kernel<1><<<dim3(NBLK), dim3(64, 16), 0, stream>>>(x, out, nullptr, stats);
    norm_atomic<<<dim3(NPX4 / 256), dim3(256), 0, stream>>>(out, stats);
  }
}